// Round 1
// baseline (998.304 us; speedup 1.0000x reference)
//
#include <hip/hip_runtime.h>
#include <hip/hip_bf16.h>
#include <math.h>

#define EDIM 128
#define NGRAPH 32

// ---------------- degree count ----------------
__global__ void k_count(const int* __restrict__ dst, int* __restrict__ deg, int E) {
    int e = blockIdx.x * blockDim.x + threadIdx.x;
    if (e < E) atomicAdd(&deg[dst[e]], 1);
}

// ---------------- single-block exclusive scan (N up to ~1M) ----------------
__global__ void k_scan(const int* __restrict__ deg, int* __restrict__ offs,
                       int* __restrict__ cursor, int N) {
    __shared__ int s[1024];
    int tid = threadIdx.x;
    int per = (N + 1023) >> 10;
    int start = tid * per; if (start > N) start = N;
    int end = start + per; if (end > N) end = N;
    int sum = 0;
    for (int i = start; i < end; i++) sum += deg[i];
    s[tid] = sum;
    __syncthreads();
    // inclusive Hillis-Steele over 1024 thread sums
    for (int off = 1; off < 1024; off <<= 1) {
        int v = s[tid];
        if (tid >= off) v += s[tid - off];
        __syncthreads();
        s[tid] = v;
        __syncthreads();
    }
    int run = s[tid] - sum;  // exclusive prefix of this thread's chunk
    for (int i = start; i < end; i++) {
        offs[i] = run; cursor[i] = run;
        run += deg[i];
    }
}

// ---------------- dinv = rsqrt(in_deg + 1) (self loop) ----------------
__global__ void k_dinv(const int* __restrict__ deg, float* __restrict__ dinv, int N) {
    int i = blockIdx.x * blockDim.x + threadIdx.x;
    if (i < N) dinv[i] = rsqrtf((float)(deg[i] + 1));
}

// ---------------- CSR fill (group edges by dst) ----------------
__global__ void k_fill(const int* __restrict__ src, const int* __restrict__ dst,
                       int* __restrict__ cursor, int* __restrict__ csr, int E) {
    int e = blockIdx.x * blockDim.x + threadIdx.x;
    if (e < E) {
        int d = dst[e];
        int pos = atomicAdd(&cursor[d], 1);
        csr[pos] = src[e];
    }
}

// ---------------- input embedding: h[n,f] = x[n]*lin_w[f] + lin_b[f] ----------------
__global__ void k_embed(const float* __restrict__ x, const float* __restrict__ w,
                        const float* __restrict__ b, float* __restrict__ h, int N) {
    int i = blockIdx.x * blockDim.x + threadIdx.x;
    if (i < N * EDIM) {
        int n = i >> 7, f = i & 127;
        h[i] = x[n] * w[f] + b[f];
    }
}

// ---------------- GEMM with row scale: g[n,:] = (h[n,:] @ W) * dinv[n] ----------------
// block: 256 threads; handles 32 nodes x 64 cols. gridDim.y=2 selects col half.
__global__ void k_gemm_scale(const float* __restrict__ h, const float* __restrict__ W,
                             const float* __restrict__ dinv, float* __restrict__ g, int N) {
    __shared__ float wl[128 * 64];   // 32 KB: W[k, cbase+cc]
    __shared__ float hl[32 * 128];   // 16 KB
    int tid = threadIdx.x;
    int cbase = blockIdx.y * 64;
    int nbase = blockIdx.x * 32;

    // load W slice (coalesced: consecutive tid -> consecutive cc)
    for (int idx = tid; idx < 128 * 64; idx += 256) {
        int k = idx >> 6, cc = idx & 63;
        wl[idx] = W[k * 128 + cbase + cc];
    }
    // load h tile
    for (int idx = tid; idx < 32 * 128; idx += 256) {
        int n = nbase + (idx >> 7);
        hl[idx] = (n < N) ? h[n * 128 + (idx & 127)] : 0.0f;
    }
    __syncthreads();

    int cc = tid & 63;
    int r  = tid >> 6;  // 0..3
    float acc[8];
#pragma unroll
    for (int i = 0; i < 8; i++) acc[i] = 0.0f;

    for (int k = 0; k < 128; k += 4) {
        float w0 = wl[(k + 0) * 64 + cc];
        float w1 = wl[(k + 1) * 64 + cc];
        float w2 = wl[(k + 2) * 64 + cc];
        float w3 = wl[(k + 3) * 64 + cc];
#pragma unroll
        for (int i = 0; i < 8; i++) {
            int nn = r + 4 * i;
            const float4 hv = *(const float4*)&hl[nn * 128 + k];
            acc[i] += hv.x * w0 + hv.y * w1 + hv.z * w2 + hv.w * w3;
        }
    }
#pragma unroll
    for (int i = 0; i < 8; i++) {
        int node = nbase + r + 4 * i;
        if (node < N) g[node * 128 + cbase + cc] = acc[i] * dinv[node];
    }
}

// ---------------- aggregate: h_out[d,:] = dinv[d]*(g[d,:] + sum_src g[s,:]) + b ----------------
// block: 256 threads = 2 nodes x 128 features
__global__ void k_aggregate(const float* __restrict__ g, const int* __restrict__ csr,
                            const int* __restrict__ offs, const int* __restrict__ deg,
                            const float* __restrict__ dinv, const float* __restrict__ b,
                            float* __restrict__ hout, int N) {
    int node = blockIdx.x * 2 + (threadIdx.x >> 7);
    int f = threadIdx.x & 127;
    if (node >= N) return;
    int start = offs[node];
    int n_e = deg[node];
    float acc = g[node * 128 + f];  // self loop
    int e = start;
    int j = 0;
    for (; j + 4 <= n_e; j += 4) {
        int s0 = csr[e], s1 = csr[e + 1], s2 = csr[e + 2], s3 = csr[e + 3];
        e += 4;
        float v0 = g[s0 * 128 + f];
        float v1 = g[s1 * 128 + f];
        float v2 = g[s2 * 128 + f];
        float v3 = g[s3 * 128 + f];
        acc += (v0 + v1) + (v2 + v3);
    }
    for (; j < n_e; j++) {
        int s = csr[e++];
        acc += g[s * 128 + f];
    }
    hout[node * 128 + f] = acc * dinv[node] + b[f];
}

// ---------------- global add pool (batch is sorted) ----------------
// block: 256 threads = 2 node-lanes x 128 features; each block covers 128 nodes
__global__ void k_pool(const float* __restrict__ h, const int* __restrict__ batch,
                       float* __restrict__ pooled, int N) {
    int f = threadIdx.x & 127;
    int sub = threadIdx.x >> 7;
    int base = blockIdx.x * 128;
    int end = base + 128; if (end > N) end = N;
    float acc = 0.0f;
    int cur = -1;
    for (int n = base + sub; n < end; n += 2) {
        int bid = batch[n];
        if (bid != cur) {
            if (cur >= 0) atomicAdd(&pooled[cur * 128 + f], acc);
            cur = bid; acc = 0.0f;
        }
        acc += h[n * 128 + f];
    }
    if (cur >= 0) atomicAdd(&pooled[cur * 128 + f], acc);
}

// ---------------- readout: out[g] = tanh(pooled@W1+b1) @ W2 + b2 ----------------
__global__ void k_readout(const float* __restrict__ pooled, const float* __restrict__ w1,
                          const float* __restrict__ b1, const float* __restrict__ w2,
                          const float* __restrict__ b2, float* __restrict__ out) {
    __shared__ float p[128];
    __shared__ float red[128];
    int gidx = blockIdx.x;
    int j = threadIdx.x;
    p[j] = pooled[gidx * 128 + j];
    __syncthreads();
    float acc = b1[j];
    for (int k = 0; k < 128; k++) acc += p[k] * w1[k * 128 + j];
    float v = tanhf(acc) * w2[j];
    red[j] = v;
    __syncthreads();
    for (int s = 64; s > 0; s >>= 1) {
        if (j < s) red[j] += red[j + s];
        __syncthreads();
    }
    if (j == 0) out[gidx] = red[0] + b2[0];
}

extern "C" void kernel_launch(void* const* d_in, const int* in_sizes, int n_in,
                              void* d_out, int out_size, void* d_ws, size_t ws_size,
                              hipStream_t stream) {
    const float* x      = (const float*)d_in[0];
    const int*   eidx   = (const int*)d_in[1];
    const int*   batch  = (const int*)d_in[2];
    const float* lin_w  = (const float*)d_in[3];
    const float* lin_b  = (const float*)d_in[4];
    const float* gcn_w  = (const float*)d_in[5];
    const float* gcn_b  = (const float*)d_in[6];
    const float* r1_w   = (const float*)d_in[7];
    const float* r1_b   = (const float*)d_in[8];
    const float* r2_w   = (const float*)d_in[9];
    const float* r2_b   = (const float*)d_in[10];

    const int N = in_sizes[0];
    const int E = in_sizes[1] / 2;
    const int* src = eidx;
    const int* dst = eidx + E;

    // workspace layout
    float* hA     = (float*)d_ws;                 // N*128
    float* hB     = hA + (size_t)N * EDIM;        // N*128
    float* dinv   = hB + (size_t)N * EDIM;        // N
    int*   deg    = (int*)(dinv + N);             // N
    int*   offs   = deg + N;                      // N
    int*   cursor = offs + N;                     // N
    int*   csr    = cursor + N;                   // E
    float* pooled = (float*)(csr + E);            // 32*128

    hipMemsetAsync(deg, 0, (size_t)N * sizeof(int), stream);
    hipMemsetAsync(pooled, 0, (size_t)NGRAPH * EDIM * sizeof(float), stream);

    k_count<<<(E + 255) / 256, 256, 0, stream>>>(dst, deg, E);
    k_scan<<<1, 1024, 0, stream>>>(deg, offs, cursor, N);
    k_dinv<<<(N + 255) / 256, 256, 0, stream>>>(deg, dinv, N);
    k_fill<<<(E + 255) / 256, 256, 0, stream>>>(src, dst, cursor, csr, E);
    k_embed<<<((size_t)N * EDIM + 255) / 256, 256, 0, stream>>>(x, lin_w, lin_b, hA, N);

    dim3 gemm_grid((N + 31) / 32, 2);
    for (int l = 0; l < 3; l++) {
        const float* W = gcn_w + (size_t)l * EDIM * EDIM;
        const float* b = gcn_b + (size_t)l * EDIM;
        k_gemm_scale<<<gemm_grid, 256, 0, stream>>>(hA, W, dinv, hB, N);
        k_aggregate<<<(N + 1) / 2, 256, 0, stream>>>(hB, csr, offs, deg, dinv, b, hA, N);
    }

    k_pool<<<(N + 127) / 128, 256, 0, stream>>>(hA, batch, pooled, N);
    k_readout<<<NGRAPH, 128, 0, stream>>>(pooled, r1_w, r1_b, r2_w, r2_b, (float*)d_out);
}

// Round 2
// 619.513 us; speedup vs baseline: 1.6114x; 1.6114x over previous
//
#include <hip/hip_runtime.h>
#include <hip/hip_bf16.h>
#include <math.h>

#define NGRAPH 32

// ---------------- degree count (in-degree over dst) ----------------
__global__ void k_count(const int* __restrict__ dst, int* __restrict__ deg, int E) {
    int e = blockIdx.x * blockDim.x + threadIdx.x;
    if (e < E) atomicAdd(&deg[dst[e]], 1);
}

// ---------------- single-block exclusive scan + dinv + q0 ----------------
__global__ void k_scan(const int* __restrict__ deg, int* __restrict__ offs,
                       int* __restrict__ cursor, const float* __restrict__ x,
                       float* __restrict__ dinv, float2* __restrict__ q0, int N) {
    __shared__ int s[1024];
    int tid = threadIdx.x;
    int per = (N + 1023) >> 10;
    int start = tid * per; if (start > N) start = N;
    int end = start + per; if (end > N) end = N;
    int sum = 0;
    for (int i = start; i < end; i++) sum += deg[i];
    s[tid] = sum;
    __syncthreads();
    for (int off = 1; off < 1024; off <<= 1) {
        int v = s[tid];
        if (tid >= off) v += s[tid - off];
        __syncthreads();
        s[tid] = v;
        __syncthreads();
    }
    int run = s[tid] - sum;  // exclusive prefix of this thread's chunk
    for (int i = start; i < end; i++) {
        offs[i] = run; cursor[i] = run;
        run += deg[i];
        float dv = rsqrtf((float)(deg[i] + 1));  // +1 self loop
        dinv[i] = dv;
        q0[i] = make_float2(x[i] * dv, dv);      // prescaled by dinv[src]
    }
}

// ---------------- CSR fill (group src by dst) ----------------
__global__ void k_fill(const int* __restrict__ src, const int* __restrict__ dst,
                       int* __restrict__ cursor, int* __restrict__ csr, int E) {
    int e = blockIdx.x * blockDim.x + threadIdx.x;
    if (e < E) {
        int d = dst[e];
        int pos = atomicAdd(&cursor[d], 1);
        csr[pos] = src[e];
    }
}

// ---------------- one hop: p'[n] = dinv[n]*(q[n] + sum q[src]); q' = p'*dinv ----------------
__global__ void k_hop(const float2* __restrict__ qin, float2* __restrict__ pout,
                      float2* __restrict__ qout, const int* __restrict__ csr,
                      const int* __restrict__ offs, const int* __restrict__ deg,
                      const float* __restrict__ dinv, int N) {
    int n = blockIdx.x * blockDim.x + threadIdx.x;
    if (n >= N) return;
    int e = offs[n];
    int ne = deg[n];
    float2 q = qin[n];
    float sx = q.x, su = q.y;   // self-loop term
    int j = 0;
    for (; j + 4 <= ne; j += 4) {
        int s0 = csr[e], s1 = csr[e + 1], s2 = csr[e + 2], s3 = csr[e + 3];
        e += 4;
        float2 a = qin[s0], b = qin[s1], c = qin[s2], d = qin[s3];
        sx += (a.x + b.x) + (c.x + d.x);
        su += (a.y + b.y) + (c.y + d.y);
    }
    for (; j < ne; j++) {
        float2 a = qin[csr[e++]];
        sx += a.x; su += a.y;
    }
    float dv = dinv[n];
    float px = dv * sx, pu = dv * su;
    pout[n] = make_float2(px, pu);
    qout[n] = make_float2(px * dv, pu * dv);
}

// ---------------- pool: 5 per-graph scalar sums ----------------
// S layout: [0:32) cnt, [32:64) u1, [64:96) u2, [96:128) u3, [128:160) v3
__global__ void k_pool(const float2* __restrict__ p1, const float2* __restrict__ p2,
                       const float2* __restrict__ p3, const int* __restrict__ batch,
                       float* __restrict__ S, int N) {
    __shared__ float ls[5 * 32];
    int tid = threadIdx.x;
    for (int i = tid; i < 160; i += 256) ls[i] = 0.0f;
    __syncthreads();
    int n = blockIdx.x * 256 + tid;
    if (n < N) {
        int g = batch[n];
        atomicAdd(&ls[0 * 32 + g], 1.0f);
        atomicAdd(&ls[1 * 32 + g], p1[n].y);
        atomicAdd(&ls[2 * 32 + g], p2[n].y);
        atomicAdd(&ls[3 * 32 + g], p3[n].y);
        atomicAdd(&ls[4 * 32 + g], p3[n].x);
    }
    __syncthreads();
    for (int i = tid; i < 160; i += 256)
        if (ls[i] != 0.0f) atomicAdd(&S[i], ls[i]);
}

// ---------------- readout: chained weight vectors + tanh MLP ----------------
// pooled[g][:] = v3*va + u3*vb + u2*vc + u1*vd + cnt*b3
// va = lin_w W1W2W3, vb = lin_b W1W2W3, vc = b1 W2W3, vd = b2 W3
__global__ void k_readout(const float* __restrict__ S,
                          const float* __restrict__ lin_w, const float* __restrict__ lin_b,
                          const float* __restrict__ gcn_w, const float* __restrict__ gcn_b,
                          const float* __restrict__ r1_w, const float* __restrict__ r1_b,
                          const float* __restrict__ r2_w, const float* __restrict__ r2_b,
                          float* __restrict__ out) {
    __shared__ float va[128], vb[128], vc[128], vd[128], pl[128], red[128];
    int j = threadIdx.x;
    va[j] = lin_w[j];
    vb[j] = lin_b[j];
    vc[j] = gcn_b[j];          // b1
    vd[j] = gcn_b[128 + j];    // b2
    __syncthreads();
    for (int l = 0; l < 3; l++) {
        const float* W = gcn_w + l * 128 * 128;
        float na = 0.f, nb = 0.f, nc = 0.f, nd = 0.f;
        for (int k = 0; k < 128; k++) {
            float w = W[k * 128 + j];
            na += va[k] * w;
            nb += vb[k] * w;
            nc += vc[k] * w;
            nd += vd[k] * w;
        }
        __syncthreads();
        va[j] = na; vb[j] = nb;
        if (l >= 1) vc[j] = nc;   // b1 goes through W2, W3 only
        if (l >= 2) vd[j] = nd;   // b2 goes through W3 only
        __syncthreads();
    }
    const float* b3 = gcn_b + 2 * 128;
    for (int g = 0; g < NGRAPH; g++) {
        float cnt = S[g], su1 = S[32 + g], su2 = S[64 + g], su3 = S[96 + g], sv3 = S[128 + g];
        pl[j] = sv3 * va[j] + su3 * vb[j] + su2 * vc[j] + su1 * vd[j] + cnt * b3[j];
        __syncthreads();
        float acc = r1_b[j];
        for (int k = 0; k < 128; k++) acc += pl[k] * r1_w[k * 128 + j];
        red[j] = tanhf(acc) * r2_w[j];
        __syncthreads();
        for (int sft = 64; sft > 0; sft >>= 1) {
            if (j < sft) red[j] += red[j + sft];
            __syncthreads();
        }
        if (j == 0) out[g] = red[0] + r2_b[0];
        __syncthreads();
    }
}

extern "C" void kernel_launch(void* const* d_in, const int* in_sizes, int n_in,
                              void* d_out, int out_size, void* d_ws, size_t ws_size,
                              hipStream_t stream) {
    const float* x     = (const float*)d_in[0];
    const int*   eidx  = (const int*)d_in[1];
    const int*   batch = (const int*)d_in[2];
    const float* lin_w = (const float*)d_in[3];
    const float* lin_b = (const float*)d_in[4];
    const float* gcn_w = (const float*)d_in[5];
    const float* gcn_b = (const float*)d_in[6];
    const float* r1_w  = (const float*)d_in[7];
    const float* r1_b  = (const float*)d_in[8];
    const float* r2_w  = (const float*)d_in[9];
    const float* r2_b  = (const float*)d_in[10];

    const int N = in_sizes[0];
    const int E = in_sizes[1] / 2;
    const int* src = eidx;
    const int* dst = eidx + E;

    // workspace layout (all offsets 8B-aligned for float2)
    char* w = (char*)d_ws;
    int*    deg    = (int*)w;                 w += (size_t)N * 4;
    int*    offs   = (int*)w;                 w += (size_t)N * 4;
    int*    cursor = (int*)w;                 w += (size_t)N * 4;
    int*    csr    = (int*)w;                 w += (size_t)E * 4;
    float*  dinv   = (float*)w;               w += (size_t)N * 4;
    float2* q0     = (float2*)w;              w += (size_t)N * 8;
    float2* p1     = (float2*)w;              w += (size_t)N * 8;
    float2* q1     = (float2*)w;              w += (size_t)N * 8;
    float2* p2     = (float2*)w;              w += (size_t)N * 8;
    float2* q2     = (float2*)w;              w += (size_t)N * 8;
    float2* p3     = (float2*)w;              w += (size_t)N * 8;
    float2* qs     = (float2*)w;              w += (size_t)N * 8;  // scratch q3 (unused)
    float*  S      = (float*)w;               w += 160 * 4;

    hipMemsetAsync(deg, 0, (size_t)N * sizeof(int), stream);
    hipMemsetAsync(S, 0, 160 * sizeof(float), stream);

    k_count<<<(E + 255) / 256, 256, 0, stream>>>(dst, deg, E);
    k_scan<<<1, 1024, 0, stream>>>(deg, offs, cursor, x, dinv, q0, N);
    k_fill<<<(E + 255) / 256, 256, 0, stream>>>(src, dst, cursor, csr, E);

    int nb = (N + 255) / 256;
    k_hop<<<nb, 256, 0, stream>>>(q0, p1, q1, csr, offs, deg, dinv, N);
    k_hop<<<nb, 256, 0, stream>>>(q1, p2, q2, csr, offs, deg, dinv, N);
    k_hop<<<nb, 256, 0, stream>>>(q2, p3, qs, csr, offs, deg, dinv, N);

    k_pool<<<nb, 256, 0, stream>>>(p1, p2, p3, batch, S, N);
    k_readout<<<1, 128, 0, stream>>>(S, lin_w, lin_b, gcn_w, gcn_b,
                                     r1_w, r1_b, r2_w, r2_b, (float*)d_out);
}

// Round 3
// 470.670 us; speedup vs baseline: 2.1210x; 1.3162x over previous
//
#include <hip/hip_runtime.h>
#include <hip/hip_bf16.h>
#include <math.h>

#define NGRAPH 32

// ---------------- degree count (in-degree over dst), int4 loads ----------------
__global__ void k_count(const int* __restrict__ dst, int* __restrict__ deg, int E) {
    int e = 4 * (blockIdx.x * blockDim.x + threadIdx.x);
    if (e + 4 <= E) {
        int4 d = *(const int4*)&dst[e];
        atomicAdd(&deg[d.x], 1);
        atomicAdd(&deg[d.y], 1);
        atomicAdd(&deg[d.z], 1);
        atomicAdd(&deg[d.w], 1);
    } else {
        for (; e < E; e++) atomicAdd(&deg[dst[e]], 1);
    }
}

// ---------------- scan phase A: per-block (256 elems) sums ----------------
__global__ void k_reduce(const int* __restrict__ deg, int* __restrict__ part, int N) {
    __shared__ int s[256];
    int tid = threadIdx.x;
    int i = blockIdx.x * 256 + tid;
    s[tid] = (i < N) ? deg[i] : 0;
    __syncthreads();
    for (int off = 128; off > 0; off >>= 1) {
        if (tid < off) s[tid] += s[tid + off];
        __syncthreads();
    }
    if (tid == 0) part[blockIdx.x] = s[0];
}

// ---------------- scan phase B: exclusive scan of <=256 partials, 1 block ----------------
__global__ void k_scanp(int* __restrict__ part, int nparts) {
    __shared__ int s[256];
    int tid = threadIdx.x;
    int v = (tid < nparts) ? part[tid] : 0;
    s[tid] = v;
    __syncthreads();
    for (int off = 1; off < 256; off <<= 1) {
        int t = (tid >= off) ? s[tid - off] : 0;
        __syncthreads();
        s[tid] += t;
        __syncthreads();
    }
    if (tid < nparts) part[tid] = s[tid] - v;  // exclusive
}

// ---------------- scan phase C: offs/cursor + dinv + q0 + per-graph counts ----------------
__global__ void k_scanfin(const int* __restrict__ deg, const int* __restrict__ part,
                          int* __restrict__ offs, int* __restrict__ cursor,
                          const float* __restrict__ x, const int* __restrict__ batch,
                          float* __restrict__ dinv, float2* __restrict__ q0,
                          float* __restrict__ S, int N) {
    __shared__ int s[256];
    __shared__ float cs[NGRAPH];
    int tid = threadIdx.x;
    if (tid < NGRAPH) cs[tid] = 0.0f;
    int i = blockIdx.x * 256 + tid;
    int v = (i < N) ? deg[i] : 0;
    s[tid] = v;
    __syncthreads();
    for (int off = 1; off < 256; off <<= 1) {
        int t = (tid >= off) ? s[tid - off] : 0;
        __syncthreads();
        s[tid] += t;
        __syncthreads();
    }
    int excl = s[tid] - v + part[blockIdx.x];
    if (i < N) {
        offs[i] = excl;
        cursor[i] = excl;
        float dv = rsqrtf((float)(v + 1));  // +1 self loop
        dinv[i] = dv;
        q0[i] = make_float2(x[i] * dv, dv);
        atomicAdd(&cs[batch[i]], 1.0f);
    }
    __syncthreads();
    if (tid < NGRAPH && cs[tid] != 0.0f) atomicAdd(&S[tid], cs[tid]);
}

// ---------------- CSR fill (group src by dst), int4 loads ----------------
__global__ void k_fill(const int* __restrict__ src, const int* __restrict__ dst,
                       int* __restrict__ cursor, int* __restrict__ csr, int E) {
    int e = 4 * (blockIdx.x * blockDim.x + threadIdx.x);
    if (e + 4 <= E) {
        int4 d = *(const int4*)&dst[e];
        int4 sv = *(const int4*)&src[e];
        csr[atomicAdd(&cursor[d.x], 1)] = sv.x;
        csr[atomicAdd(&cursor[d.y], 1)] = sv.y;
        csr[atomicAdd(&cursor[d.z], 1)] = sv.z;
        csr[atomicAdd(&cursor[d.w], 1)] = sv.w;
    } else {
        for (; e < E; e++) {
            int d = dst[e];
            csr[atomicAdd(&cursor[d], 1)] = src[e];
        }
    }
}

// ---------------- one hop, 16 lanes per node, pooling fused ----------------
// p[n] = dinv[n]*(q[n] + sum_src q[s]);  q' = p*dinv
// Accumulates sum over nodes of p.y into S[soff+g]; if !WRITE_Q also p.x into S[128+g].
template <int WRITE_Q>
__global__ void k_hop(const float2* __restrict__ qin, float2* __restrict__ qout,
                      const int* __restrict__ csr, const int* __restrict__ offs,
                      const int* __restrict__ deg, const float* __restrict__ dinv,
                      const int* __restrict__ batch, float* __restrict__ S,
                      int soff, int N) {
    __shared__ float su[NGRAPH];
    __shared__ float sv[NGRAPH];
    int tid = threadIdx.x;
    if (tid < NGRAPH) { su[tid] = 0.0f; sv[tid] = 0.0f; }
    __syncthreads();
    int lane = tid & 15;
    int node = blockIdx.x * 16 + (tid >> 4);
    float sx = 0.0f, suv = 0.0f;
    if (node < N) {
        int e = offs[node], ne = deg[node];
        for (int j = lane; j < ne; j += 16) {
            int s = csr[e + j];
            float2 q = qin[s];
            sx += q.x; suv += q.y;
        }
    }
#pragma unroll
    for (int m = 8; m > 0; m >>= 1) {
        sx  += __shfl_xor(sx, m);
        suv += __shfl_xor(suv, m);
    }
    if (node < N && lane == 0) {
        float2 qs = qin[node];
        float dv = dinv[node];
        float px = dv * (sx + qs.x), pu = dv * (suv + qs.y);
        int g = batch[node];
        atomicAdd(&su[g], pu);
        if (WRITE_Q) qout[node] = make_float2(px * dv, pu * dv);
        else         atomicAdd(&sv[g], px);
    }
    __syncthreads();
    if (tid < NGRAPH) {
        if (su[tid] != 0.0f) atomicAdd(&S[soff + tid], su[tid]);
        if (!WRITE_Q && sv[tid] != 0.0f) atomicAdd(&S[128 + tid], sv[tid]);
    }
}

// ---------------- readout: chained weight vectors + tanh MLP ----------------
// pooled[g][:] = v3*va + u3*vb + u2*vc + u1*vd + cnt*b3
__global__ void k_readout(const float* __restrict__ S,
                          const float* __restrict__ lin_w, const float* __restrict__ lin_b,
                          const float* __restrict__ gcn_w, const float* __restrict__ gcn_b,
                          const float* __restrict__ r1_w, const float* __restrict__ r1_b,
                          const float* __restrict__ r2_w, const float* __restrict__ r2_b,
                          float* __restrict__ out) {
    __shared__ float va[128], vb[128], vc[128], vd[128], pl[128], red[128];
    int j = threadIdx.x;
    va[j] = lin_w[j];
    vb[j] = lin_b[j];
    vc[j] = gcn_b[j];          // b1
    vd[j] = gcn_b[128 + j];    // b2
    __syncthreads();
    for (int l = 0; l < 3; l++) {
        const float* W = gcn_w + l * 128 * 128;
        float na = 0.f, nb = 0.f, nc = 0.f, nd = 0.f;
        for (int k = 0; k < 128; k++) {
            float w = W[k * 128 + j];
            na += va[k] * w;
            nb += vb[k] * w;
            nc += vc[k] * w;
            nd += vd[k] * w;
        }
        __syncthreads();
        va[j] = na; vb[j] = nb;
        if (l >= 1) vc[j] = nc;   // b1 goes through W2, W3 only
        if (l >= 2) vd[j] = nd;   // b2 goes through W3 only
        __syncthreads();
    }
    const float* b3 = gcn_b + 2 * 128;
    for (int g = 0; g < NGRAPH; g++) {
        float cnt = S[g], su1 = S[32 + g], su2 = S[64 + g], su3 = S[96 + g], sv3 = S[128 + g];
        pl[j] = sv3 * va[j] + su3 * vb[j] + su2 * vc[j] + su1 * vd[j] + cnt * b3[j];
        __syncthreads();
        float acc = r1_b[j];
        for (int k = 0; k < 128; k++) acc += pl[k] * r1_w[k * 128 + j];
        red[j] = tanhf(acc) * r2_w[j];
        __syncthreads();
        for (int sft = 64; sft > 0; sft >>= 1) {
            if (j < sft) red[j] += red[j + sft];
            __syncthreads();
        }
        if (j == 0) out[g] = red[0] + r2_b[0];
        __syncthreads();
    }
}

extern "C" void kernel_launch(void* const* d_in, const int* in_sizes, int n_in,
                              void* d_out, int out_size, void* d_ws, size_t ws_size,
                              hipStream_t stream) {
    const float* x     = (const float*)d_in[0];
    const int*   eidx  = (const int*)d_in[1];
    const int*   batch = (const int*)d_in[2];
    const float* lin_w = (const float*)d_in[3];
    const float* lin_b = (const float*)d_in[4];
    const float* gcn_w = (const float*)d_in[5];
    const float* gcn_b = (const float*)d_in[6];
    const float* r1_w  = (const float*)d_in[7];
    const float* r1_b  = (const float*)d_in[8];
    const float* r2_w  = (const float*)d_in[9];
    const float* r2_b  = (const float*)d_in[10];

    const int N = in_sizes[0];
    const int E = in_sizes[1] / 2;
    const int* src = eidx;
    const int* dst = eidx + E;
    const int nparts = (N + 255) / 256;  // 196 for N=50000

    // workspace layout (8B aligned)
    char* w = (char*)d_ws;
    int*    deg    = (int*)w;    w += (size_t)N * 4;
    int*    offs   = (int*)w;    w += (size_t)N * 4;
    int*    cursor = (int*)w;    w += (size_t)N * 4;
    int*    part   = (int*)w;    w += 256 * 4;
    int*    csr    = (int*)w;    w += (size_t)E * 4;
    float*  dinv   = (float*)w;  w += (size_t)N * 4;
    float2* q0     = (float2*)w; w += (size_t)N * 8;
    float2* q1     = (float2*)w; w += (size_t)N * 8;
    float2* q2     = (float2*)w; w += (size_t)N * 8;
    float*  S      = (float*)w;  w += 160 * 4;

    hipMemsetAsync(deg, 0, (size_t)N * sizeof(int), stream);
    hipMemsetAsync(S, 0, 160 * sizeof(float), stream);

    k_count<<<(E / 4 + 255) / 256, 256, 0, stream>>>(dst, deg, E);
    k_reduce<<<nparts, 256, 0, stream>>>(deg, part, N);
    k_scanp<<<1, 256, 0, stream>>>(part, nparts);
    k_scanfin<<<nparts, 256, 0, stream>>>(deg, part, offs, cursor, x, batch, dinv, q0, S, N);
    k_fill<<<(E / 4 + 255) / 256, 256, 0, stream>>>(src, dst, cursor, csr, E);

    int hop_blocks = (N + 15) / 16;
    k_hop<1><<<hop_blocks, 256, 0, stream>>>(q0, q1, csr, offs, deg, dinv, batch, S, 32, N);
    k_hop<1><<<hop_blocks, 256, 0, stream>>>(q1, q2, csr, offs, deg, dinv, batch, S, 64, N);
    k_hop<0><<<hop_blocks, 256, 0, stream>>>(q2, (float2*)nullptr, csr, offs, deg, dinv, batch, S, 96, N);

    k_readout<<<1, 128, 0, stream>>>(S, lin_w, lin_b, gcn_w, gcn_b,
                                     r1_w, r1_b, r2_w, r2_b, (float*)d_out);
}

// Round 4
// 345.506 us; speedup vs baseline: 2.8894x; 1.3623x over previous
//
#include <hip/hip_runtime.h>
#include <hip/hip_bf16.h>
#include <math.h>

#define NGRAPH 32
#define EPB 4096   // edges per partition block

// ---------------- pass 1a: global bucket histogram (bucket = dst>>8) ----------------
__global__ void k_hist(const int* __restrict__ dst, int* __restrict__ ghist, int E) {
    __shared__ int hist[256];
    int tid = threadIdx.x;
    hist[tid] = 0;
    __syncthreads();
    int e = 4 * (blockIdx.x * blockDim.x + tid);
    if (e + 4 <= E) {
        int4 d = *(const int4*)&dst[e];
        atomicAdd(&hist[d.x >> 8], 1);
        atomicAdd(&hist[d.y >> 8], 1);
        atomicAdd(&hist[d.z >> 8], 1);
        atomicAdd(&hist[d.w >> 8], 1);
    } else {
        for (; e < E; e++) atomicAdd(&hist[dst[e] >> 8], 1);
    }
    __syncthreads();
    if (hist[tid] > 0) atomicAdd(&ghist[tid], hist[tid]);
}

// ---------------- pass 1b: exclusive scan of bucket counts (1 block) ----------------
__global__ void k_scan196(const int* __restrict__ ghist, int* __restrict__ gofs,
                          int* __restrict__ gcursor, int NB, int E) {
    __shared__ int s[256];
    int tid = threadIdx.x;
    int v = (tid < NB) ? ghist[tid] : 0;
    s[tid] = v;
    __syncthreads();
    for (int off = 1; off < 256; off <<= 1) {
        int t = (tid >= off) ? s[tid - off] : 0;
        __syncthreads();
        s[tid] += t;
        __syncthreads();
    }
    int excl = s[tid] - v;           // exclusive prefix; for tid >= NB this equals E
    if (tid <= NB) gofs[tid] = excl; // gofs[NB] = E sentinel
    if (tid < NB)  gcursor[tid] = excl;
}

// ---------------- pass 1c: partition edges into bucket-contiguous ranges ----------------
__global__ void k_part(const int* __restrict__ src, const int* __restrict__ dst,
                       int* __restrict__ gcursor, int2* __restrict__ sorted, int E) {
    __shared__ int hist[256], base[256], lcur[256];
    int tid = threadIdx.x;
    int e0 = blockIdx.x * EPB;
    hist[tid] = 0;
    __syncthreads();
    int d[16], s[16];
#pragma unroll
    for (int k = 0; k < 16; k++) {
        int e = e0 + k * 256 + tid;
        if (e < E) {
            d[k] = dst[e];
            s[k] = src[e];
            atomicAdd(&hist[d[k] >> 8], 1);
        }
    }
    __syncthreads();
    int h = hist[tid];
    if (h > 0) base[tid] = atomicAdd(&gcursor[tid], h);  // reserve contiguous sub-range
    lcur[tid] = 0;
    __syncthreads();
#pragma unroll
    for (int k = 0; k < 16; k++) {
        int e = e0 + k * 256 + tid;
        if (e < E) {
            int bk = d[k] >> 8;
            int pos = base[bk] + atomicAdd(&lcur[bk], 1);
            sorted[pos] = make_int2(s[k], d[k]);
        }
    }
}

// ---------------- pass 2: per-bucket CSR build + deg/dinv/q0/per-graph counts ----------------
__global__ void k_bucket(const int2* __restrict__ sorted, const int* __restrict__ gofs,
                         const float* __restrict__ x, const int* __restrict__ batch,
                         int* __restrict__ offs, int* __restrict__ deg,
                         float* __restrict__ dinv, float2* __restrict__ q0,
                         int* __restrict__ csr, float* __restrict__ S, int N) {
    __shared__ int cnt[256], lofs[256], lcur[256];
    __shared__ float cs[NGRAPH];
    int tid = threadIdx.x;
    int b = blockIdx.x;
    int start = gofs[b], end = gofs[b + 1];
    cnt[tid] = 0;
    if (tid < NGRAPH) cs[tid] = 0.f;
    __syncthreads();
    for (int e = start + tid; e < end; e += 256)
        atomicAdd(&cnt[sorted[e].y & 255], 1);
    __syncthreads();
    int v = cnt[tid];
    lofs[tid] = v;
    __syncthreads();
    for (int off = 1; off < 256; off <<= 1) {
        int t = (tid >= off) ? lofs[tid - off] : 0;
        __syncthreads();
        lofs[tid] += t;
        __syncthreads();
    }
    int excl = lofs[tid] - v;
    lcur[tid] = excl;
    int node = b * 256 + tid;
    if (node < N) {
        deg[node] = v;
        offs[node] = start + excl;
        float dv = rsqrtf((float)(v + 1));   // +1 self loop
        dinv[node] = dv;
        q0[node] = make_float2(x[node] * dv, dv);
        atomicAdd(&cs[batch[node]], 1.f);
    }
    __syncthreads();
    for (int e = start + tid; e < end; e += 256) {
        int2 sd = sorted[e];
        int pos = start + atomicAdd(&lcur[sd.y & 255], 1);
        csr[pos] = sd.x;
    }
    if (tid < NGRAPH && cs[tid] != 0.f) atomicAdd(&S[tid], cs[tid]);
}

// ---------------- one hop, 16 lanes per node, pooling fused ----------------
template <int WRITE_Q>
__global__ void k_hop(const float2* __restrict__ qin, float2* __restrict__ qout,
                      const int* __restrict__ csr, const int* __restrict__ offs,
                      const int* __restrict__ deg, const float* __restrict__ dinv,
                      const int* __restrict__ batch, float* __restrict__ S,
                      int soff, int N) {
    __shared__ float su[NGRAPH];
    __shared__ float sv[NGRAPH];
    int tid = threadIdx.x;
    if (tid < NGRAPH) { su[tid] = 0.0f; sv[tid] = 0.0f; }
    __syncthreads();
    int lane = tid & 15;
    int node = blockIdx.x * 16 + (tid >> 4);
    float sx = 0.0f, suv = 0.0f;
    if (node < N) {
        int e = offs[node], ne = deg[node];
        for (int j = lane; j < ne; j += 16) {
            int s = csr[e + j];
            float2 q = qin[s];
            sx += q.x; suv += q.y;
        }
    }
#pragma unroll
    for (int m = 8; m > 0; m >>= 1) {
        sx  += __shfl_xor(sx, m);
        suv += __shfl_xor(suv, m);
    }
    if (node < N && lane == 0) {
        float2 qs = qin[node];
        float dv = dinv[node];
        float px = dv * (sx + qs.x), pu = dv * (suv + qs.y);
        int g = batch[node];
        atomicAdd(&su[g], pu);
        if (WRITE_Q) qout[node] = make_float2(px * dv, pu * dv);
        else         atomicAdd(&sv[g], px);
    }
    __syncthreads();
    if (tid < NGRAPH) {
        if (su[tid] != 0.0f) atomicAdd(&S[soff + tid], su[tid]);
        if (!WRITE_Q && sv[tid] != 0.0f) atomicAdd(&S[128 + tid], sv[tid]);
    }
}

// ---------------- readout: chained weight vectors + tanh MLP ----------------
__global__ void k_readout(const float* __restrict__ S,
                          const float* __restrict__ lin_w, const float* __restrict__ lin_b,
                          const float* __restrict__ gcn_w, const float* __restrict__ gcn_b,
                          const float* __restrict__ r1_w, const float* __restrict__ r1_b,
                          const float* __restrict__ r2_w, const float* __restrict__ r2_b,
                          float* __restrict__ out) {
    __shared__ float va[128], vb[128], vc[128], vd[128], pl[128], red[128];
    int j = threadIdx.x;
    va[j] = lin_w[j];
    vb[j] = lin_b[j];
    vc[j] = gcn_b[j];          // b1
    vd[j] = gcn_b[128 + j];    // b2
    __syncthreads();
    for (int l = 0; l < 3; l++) {
        const float* W = gcn_w + l * 128 * 128;
        float na = 0.f, nb = 0.f, nc = 0.f, nd = 0.f;
        for (int k = 0; k < 128; k++) {
            float w = W[k * 128 + j];
            na += va[k] * w;
            nb += vb[k] * w;
            nc += vc[k] * w;
            nd += vd[k] * w;
        }
        __syncthreads();
        va[j] = na; vb[j] = nb;
        if (l >= 1) vc[j] = nc;   // b1 goes through W2, W3 only
        if (l >= 2) vd[j] = nd;   // b2 goes through W3 only
        __syncthreads();
    }
    const float* b3 = gcn_b + 2 * 128;
    for (int g = 0; g < NGRAPH; g++) {
        float cnt = S[g], su1 = S[32 + g], su2 = S[64 + g], su3 = S[96 + g], sv3 = S[128 + g];
        pl[j] = sv3 * va[j] + su3 * vb[j] + su2 * vc[j] + su1 * vd[j] + cnt * b3[j];
        __syncthreads();
        float acc = r1_b[j];
        for (int k = 0; k < 128; k++) acc += pl[k] * r1_w[k * 128 + j];
        red[j] = tanhf(acc) * r2_w[j];
        __syncthreads();
        for (int sft = 64; sft > 0; sft >>= 1) {
            if (j < sft) red[j] += red[j + sft];
            __syncthreads();
        }
        if (j == 0) out[g] = red[0] + r2_b[0];
        __syncthreads();
    }
}

extern "C" void kernel_launch(void* const* d_in, const int* in_sizes, int n_in,
                              void* d_out, int out_size, void* d_ws, size_t ws_size,
                              hipStream_t stream) {
    const float* x     = (const float*)d_in[0];
    const int*   eidx  = (const int*)d_in[1];
    const int*   batch = (const int*)d_in[2];
    const float* lin_w = (const float*)d_in[3];
    const float* lin_b = (const float*)d_in[4];
    const float* gcn_w = (const float*)d_in[5];
    const float* gcn_b = (const float*)d_in[6];
    const float* r1_w  = (const float*)d_in[7];
    const float* r1_b  = (const float*)d_in[8];
    const float* r2_w  = (const float*)d_in[9];
    const float* r2_b  = (const float*)d_in[10];

    const int N = in_sizes[0];
    const int E = in_sizes[1] / 2;
    const int* src = eidx;
    const int* dst = eidx + E;
    const int NB = (N + 255) / 256;  // 196 buckets

    // workspace layout (8B aligned; N even so N*4 is 8B-multiple)
    char* w = (char*)d_ws;
    int2*   sorted  = (int2*)w;   w += (size_t)E * 8;
    int*    csr     = (int*)w;    w += (size_t)E * 4;
    int*    offs    = (int*)w;    w += (size_t)N * 4;
    int*    deg     = (int*)w;    w += (size_t)N * 4;
    float*  dinv    = (float*)w;  w += (size_t)N * 4;
    float2* q0      = (float2*)w; w += (size_t)N * 8;
    float2* q1      = (float2*)w; w += (size_t)N * 8;
    float2* q2      = (float2*)w; w += (size_t)N * 8;
    int*    ghist   = (int*)w;    w += 256 * 4;
    int*    gofs    = (int*)w;    w += 260 * 4;
    int*    gcursor = (int*)w;    w += 256 * 4;
    float*  S       = (float*)w;  w += 160 * 4;

    hipMemsetAsync(ghist, 0, 256 * sizeof(int), stream);
    hipMemsetAsync(S, 0, 160 * sizeof(float), stream);

    k_hist<<<(E / 4 + 255) / 256, 256, 0, stream>>>(dst, ghist, E);
    k_scan196<<<1, 256, 0, stream>>>(ghist, gofs, gcursor, NB, E);
    k_part<<<(E + EPB - 1) / EPB, 256, 0, stream>>>(src, dst, gcursor, sorted, E);
    k_bucket<<<NB, 256, 0, stream>>>(sorted, gofs, x, batch, offs, deg, dinv, q0, csr, S, N);

    int hop_blocks = (N + 15) / 16;
    k_hop<1><<<hop_blocks, 256, 0, stream>>>(q0, q1, csr, offs, deg, dinv, batch, S, 32, N);
    k_hop<1><<<hop_blocks, 256, 0, stream>>>(q1, q2, csr, offs, deg, dinv, batch, S, 64, N);
    k_hop<0><<<hop_blocks, 256, 0, stream>>>(q2, (float2*)nullptr, csr, offs, deg, dinv, batch, S, 96, N);

    k_readout<<<1, 128, 0, stream>>>(S, lin_w, lin_b, gcn_w, gcn_b,
                                     r1_w, r1_b, r2_w, r2_b, (float*)d_out);
}

// Round 5
// 294.819 us; speedup vs baseline: 3.3862x; 1.1719x over previous
//
#include <hip/hip_runtime.h>
#include <hip/hip_bf16.h>
#include <math.h>

#define NGRAPH 32
#define EPB 4096   // edges per partition block

// ---------------- pass 1a: global bucket histogram (bucket = dst>>8) ----------------
__global__ void k_hist(const int* __restrict__ dst, int* __restrict__ ghist, int E) {
    __shared__ int hist[256];
    int tid = threadIdx.x;
    hist[tid] = 0;
    __syncthreads();
    int e = 4 * (blockIdx.x * blockDim.x + tid);
    if (e + 4 <= E) {
        int4 d = *(const int4*)&dst[e];
        atomicAdd(&hist[d.x >> 8], 1);
        atomicAdd(&hist[d.y >> 8], 1);
        atomicAdd(&hist[d.z >> 8], 1);
        atomicAdd(&hist[d.w >> 8], 1);
    } else {
        for (; e < E; e++) atomicAdd(&hist[dst[e] >> 8], 1);
    }
    __syncthreads();
    if (hist[tid] > 0) atomicAdd(&ghist[tid], hist[tid]);
}

// ---------------- pass 1b: exclusive scan of bucket counts (1 block) ----------------
__global__ void k_scan196(const int* __restrict__ ghist, int* __restrict__ gofs,
                          int* __restrict__ gcursor, int NB, int E) {
    __shared__ int s[256];
    int tid = threadIdx.x;
    int v = (tid < NB) ? ghist[tid] : 0;
    s[tid] = v;
    __syncthreads();
    for (int off = 1; off < 256; off <<= 1) {
        int t = (tid >= off) ? s[tid - off] : 0;
        __syncthreads();
        s[tid] += t;
        __syncthreads();
    }
    int excl = s[tid] - v;           // exclusive prefix; for tid >= NB this equals E
    if (tid <= NB) gofs[tid] = excl; // gofs[NB] = E sentinel
    if (tid < NB)  gcursor[tid] = excl;
}

// ---------------- pass 1c: partition edges into bucket-contiguous ranges ----------------
__global__ void k_part(const int* __restrict__ src, const int* __restrict__ dst,
                       int* __restrict__ gcursor, int2* __restrict__ sorted, int E) {
    __shared__ int hist[256], base[256], lcur[256];
    int tid = threadIdx.x;
    int e0 = blockIdx.x * EPB;
    hist[tid] = 0;
    __syncthreads();
    int d[16], s[16];
#pragma unroll
    for (int k = 0; k < 16; k++) {
        int e = e0 + k * 256 + tid;
        if (e < E) {
            d[k] = dst[e];
            s[k] = src[e];
            atomicAdd(&hist[d[k] >> 8], 1);
        }
    }
    __syncthreads();
    int h = hist[tid];
    if (h > 0) base[tid] = atomicAdd(&gcursor[tid], h);  // reserve contiguous sub-range
    lcur[tid] = 0;
    __syncthreads();
#pragma unroll
    for (int k = 0; k < 16; k++) {
        int e = e0 + k * 256 + tid;
        if (e < E) {
            int bk = d[k] >> 8;
            int pos = base[bk] + atomicAdd(&lcur[bk], 1);
            sorted[pos] = make_int2(s[k], d[k]);
        }
    }
}

// ---------------- pass 2: per-bucket CSR build + deg/dinv/q0/per-graph counts ----------------
__global__ void k_bucket(const int2* __restrict__ sorted, const int* __restrict__ gofs,
                         const float* __restrict__ x, const int* __restrict__ batch,
                         int* __restrict__ offs, int* __restrict__ deg,
                         float* __restrict__ dinv, float2* __restrict__ q0,
                         int* __restrict__ csr, float* __restrict__ S, int N) {
    __shared__ int cnt[256], lofs[256], lcur[256];
    __shared__ float cs[NGRAPH];
    int tid = threadIdx.x;
    int b = blockIdx.x;
    int start = gofs[b], end = gofs[b + 1];
    cnt[tid] = 0;
    if (tid < NGRAPH) cs[tid] = 0.f;
    __syncthreads();
    for (int e = start + tid; e < end; e += 256)
        atomicAdd(&cnt[sorted[e].y & 255], 1);
    __syncthreads();
    int v = cnt[tid];
    lofs[tid] = v;
    __syncthreads();
    for (int off = 1; off < 256; off <<= 1) {
        int t = (tid >= off) ? lofs[tid - off] : 0;
        __syncthreads();
        lofs[tid] += t;
        __syncthreads();
    }
    int excl = lofs[tid] - v;
    lcur[tid] = excl;
    int node = b * 256 + tid;
    if (node < N) {
        deg[node] = v;
        offs[node] = start + excl;
        float dv = rsqrtf((float)(v + 1));   // +1 self loop
        dinv[node] = dv;
        q0[node] = make_float2(x[node] * dv, dv);
        atomicAdd(&cs[batch[node]], 1.f);
    }
    __syncthreads();
    for (int e = start + tid; e < end; e += 256) {
        int2 sd = sorted[e];
        int pos = start + atomicAdd(&lcur[sd.y & 255], 1);
        csr[pos] = sd.x;
    }
    if (tid < NGRAPH && cs[tid] != 0.f) atomicAdd(&S[tid], cs[tid]);
}

// ---------------- one hop, 16 lanes per node, pooling fused ----------------
template <int WRITE_Q>
__global__ void k_hop(const float2* __restrict__ qin, float2* __restrict__ qout,
                      const int* __restrict__ csr, const int* __restrict__ offs,
                      const int* __restrict__ deg, const float* __restrict__ dinv,
                      const int* __restrict__ batch, float* __restrict__ S,
                      int soff, int N) {
    __shared__ float su[NGRAPH];
    __shared__ float sv[NGRAPH];
    int tid = threadIdx.x;
    if (tid < NGRAPH) { su[tid] = 0.0f; sv[tid] = 0.0f; }
    __syncthreads();
    int lane = tid & 15;
    int node = blockIdx.x * 16 + (tid >> 4);
    float sx = 0.0f, suv = 0.0f;
    if (node < N) {
        int e = offs[node], ne = deg[node];
        for (int j = lane; j < ne; j += 16) {
            int s = csr[e + j];
            float2 q = qin[s];
            sx += q.x; suv += q.y;
        }
    }
#pragma unroll
    for (int m = 8; m > 0; m >>= 1) {
        sx  += __shfl_xor(sx, m);
        suv += __shfl_xor(suv, m);
    }
    if (node < N && lane == 0) {
        float2 qs = qin[node];
        float dv = dinv[node];
        float px = dv * (sx + qs.x), pu = dv * (suv + qs.y);
        int g = batch[node];
        atomicAdd(&su[g], pu);
        if (WRITE_Q) qout[node] = make_float2(px * dv, pu * dv);
        else         atomicAdd(&sv[g], px);
    }
    __syncthreads();
    if (tid < NGRAPH) {
        if (su[tid] != 0.0f) atomicAdd(&S[soff + tid], su[tid]);
        if (!WRITE_Q && sv[tid] != 0.0f) atomicAdd(&S[128 + tid], sv[tid]);
    }
}

// ---------------- readout A: chain weight vectors through W1..W3 (1 block) ----------------
// va = lin_w W1W2W3, vb = lin_b W1W2W3, vc = b1 W2W3, vd = b2 W3  -> chainv[0..3][128]
__global__ void k_chain(const float* __restrict__ lin_w, const float* __restrict__ lin_b,
                        const float* __restrict__ gcn_w, const float* __restrict__ gcn_b,
                        float* __restrict__ chainv) {
    __shared__ float va[128], vb[128], vc[128], vd[128];
    int j = threadIdx.x;
    va[j] = lin_w[j];
    vb[j] = lin_b[j];
    vc[j] = gcn_b[j];          // b1
    vd[j] = gcn_b[128 + j];    // b2
    __syncthreads();
    for (int l = 0; l < 3; l++) {
        const float* W = gcn_w + l * 128 * 128;
        float na = 0.f, nb = 0.f, nc = 0.f, nd = 0.f;
        for (int k = 0; k < 128; k++) {
            float w = W[k * 128 + j];
            na += va[k] * w;
            nb += vb[k] * w;
            nc += vc[k] * w;
            nd += vd[k] * w;
        }
        __syncthreads();
        va[j] = na; vb[j] = nb;
        if (l >= 1) vc[j] = nc;   // b1 goes through W2, W3 only
        if (l >= 2) vd[j] = nd;   // b2 goes through W3 only
        __syncthreads();
    }
    chainv[j] = va[j];
    chainv[128 + j] = vb[j];
    chainv[256 + j] = vc[j];
    chainv[384 + j] = vd[j];
}

// ---------------- readout B: per-graph MLP (32 blocks x 128 threads) ----------------
__global__ void k_mlp(const float* __restrict__ S, const float* __restrict__ chainv,
                      const float* __restrict__ gcn_b,
                      const float* __restrict__ r1_w, const float* __restrict__ r1_b,
                      const float* __restrict__ r2_w, const float* __restrict__ r2_b,
                      float* __restrict__ out) {
    __shared__ float pl[128], red[128];
    int j = threadIdx.x;
    int g = blockIdx.x;
    float cnt = S[g], su1 = S[32 + g], su2 = S[64 + g], su3 = S[96 + g], sv3 = S[128 + g];
    const float* b3 = gcn_b + 2 * 128;
    pl[j] = sv3 * chainv[j] + su3 * chainv[128 + j] + su2 * chainv[256 + j]
          + su1 * chainv[384 + j] + cnt * b3[j];
    __syncthreads();
    float acc = r1_b[j];
#pragma unroll 4
    for (int k = 0; k < 128; k++) acc += pl[k] * r1_w[k * 128 + j];
    red[j] = tanhf(acc) * r2_w[j];
    __syncthreads();
    for (int sft = 64; sft > 0; sft >>= 1) {
        if (j < sft) red[j] += red[j + sft];
        __syncthreads();
    }
    if (j == 0) out[g] = red[0] + r2_b[0];
}

extern "C" void kernel_launch(void* const* d_in, const int* in_sizes, int n_in,
                              void* d_out, int out_size, void* d_ws, size_t ws_size,
                              hipStream_t stream) {
    const float* x     = (const float*)d_in[0];
    const int*   eidx  = (const int*)d_in[1];
    const int*   batch = (const int*)d_in[2];
    const float* lin_w = (const float*)d_in[3];
    const float* lin_b = (const float*)d_in[4];
    const float* gcn_w = (const float*)d_in[5];
    const float* gcn_b = (const float*)d_in[6];
    const float* r1_w  = (const float*)d_in[7];
    const float* r1_b  = (const float*)d_in[8];
    const float* r2_w  = (const float*)d_in[9];
    const float* r2_b  = (const float*)d_in[10];

    const int N = in_sizes[0];
    const int E = in_sizes[1] / 2;
    const int* src = eidx;
    const int* dst = eidx + E;
    const int NB = (N + 255) / 256;  // 196 buckets

    // workspace layout (8B aligned; N even so N*4 is 8B-multiple)
    char* w = (char*)d_ws;
    int2*   sorted  = (int2*)w;   w += (size_t)E * 8;
    int*    csr     = (int*)w;    w += (size_t)E * 4;
    int*    offs    = (int*)w;    w += (size_t)N * 4;
    int*    deg     = (int*)w;    w += (size_t)N * 4;
    float*  dinv    = (float*)w;  w += (size_t)N * 4;
    float2* q0      = (float2*)w; w += (size_t)N * 8;
    float2* q1      = (float2*)w; w += (size_t)N * 8;
    float2* q2      = (float2*)w; w += (size_t)N * 8;
    int*    ghist   = (int*)w;    w += 256 * 4;
    int*    gofs    = (int*)w;    w += 260 * 4;
    int*    gcursor = (int*)w;    w += 256 * 4;
    float*  S       = (float*)w;  w += 160 * 4;
    float*  chainv  = (float*)w;  w += 512 * 4;

    hipMemsetAsync(ghist, 0, 256 * sizeof(int), stream);
    hipMemsetAsync(S, 0, 160 * sizeof(float), stream);

    k_hist<<<(E / 4 + 255) / 256, 256, 0, stream>>>(dst, ghist, E);
    k_scan196<<<1, 256, 0, stream>>>(ghist, gofs, gcursor, NB, E);
    k_part<<<(E + EPB - 1) / EPB, 256, 0, stream>>>(src, dst, gcursor, sorted, E);
    k_bucket<<<NB, 256, 0, stream>>>(sorted, gofs, x, batch, offs, deg, dinv, q0, csr, S, N);
    k_chain<<<1, 128, 0, stream>>>(lin_w, lin_b, gcn_w, gcn_b, chainv);  // overlaps with graph build

    int hop_blocks = (N + 15) / 16;
    k_hop<1><<<hop_blocks, 256, 0, stream>>>(q0, q1, csr, offs, deg, dinv, batch, S, 32, N);
    k_hop<1><<<hop_blocks, 256, 0, stream>>>(q1, q2, csr, offs, deg, dinv, batch, S, 64, N);
    k_hop<0><<<hop_blocks, 256, 0, stream>>>(q2, (float2*)nullptr, csr, offs, deg, dinv, batch, S, 96, N);

    k_mlp<<<NGRAPH, 128, 0, stream>>>(S, chainv, gcn_b, r1_w, r1_b, r2_w, r2_b, (float*)d_out);
}